// Round 5
// baseline (339.943 us; speedup 1.0000x reference)
//
#include <hip/hip_runtime.h>

static constexpr int Lc = 512;
static constexpr int Bc = 256;
static constexpr int Tc = 128;

typedef _Float16 half2_t __attribute__((ext_vector_type(2)));
typedef __fp16   fp16x2_t __attribute__((ext_vector_type(2)));   // builtin's type

__device__ __forceinline__ float fdot2(half2_t a, half2_t b, float c) {
#if __has_builtin(__builtin_amdgcn_fdot2)
  return __builtin_amdgcn_fdot2(a, b, c, false);
#else
  return fmaf((float)a[0], (float)b[0], fmaf((float)a[1], (float)b[1], c));
#endif
}

__device__ __forceinline__ unsigned pack_h2(float a, float b) {
  union { fp16x2_t h; unsigned u; } cv;
  cv.h = __builtin_amdgcn_cvt_pkrtz(a, b);   // v_cvt_pkrtz_f16_f32
  return cv.u;
}

// ONE WAVE per batch element: 256 blocks x 64 threads. No __syncthreads in
// the recurrence; single-wave LDS round-trip broadcasts p each step.
// Lane l owns output tags j0=2l, j1=2l+1 with the FULL i-reduction done via
// v_dot2_f32_f16 against an f16 E-column pair held in 128 VGPRs.
__launch_bounds__(64, 1)
__global__ void crf_llh_kernel(const float* __restrict__ emis,
                               const int* __restrict__ tags,
                               const int* __restrict__ mask,
                               const float* __restrict__ startT,
                               const float* __restrict__ endT,
                               const float* __restrict__ trans,
                               float* __restrict__ partial)
{
  const int b  = blockIdx.x;
  const int l  = threadIdx.x;       // lane 0..63
  const int j0 = 2 * l;
  const int j1 = 2 * l + 1;

  __shared__ __align__(16) unsigned p_lds[2][64];   // packed f16x2, 2x256B

  // ---------------- numerator (gold-path score), 8 t's per lane ----------
  float v = 0.f, c = 0.f;
  for (int t = l; t < Lc; t += 64) {
    const float mf  = (float)mask[t * Bc + b];
    const int tag_t = tags[t * Bc + b];
    float e = emis[((size_t)t * Bc + b) * Tc + tag_t] * mf;
    if (t >= 1) e += trans[tags[(t - 1) * Bc + b] * Tc + tag_t] * mf;
    v += e; c += mf;
  }
  #pragma unroll
  for (int o = 1; o < 64; o <<= 1) {
    v += __shfl_xor(v, o);
    c += __shfl_xor(c, o);
  }
  float score = 0.f;   // valid on lane 0
  if (l == 0) {
    const int last_idx = (int)(c + 0.5f) - 1;
    score = v + startT[tags[b]] + endT[tags[last_idx * Bc + b]];
  }

  // ---------------- E columns as f16 pairs: 128 VGPRs ----------------
  // E0[k] = (exp(tr[2k][j0]), exp(tr[2k+1][j0])), same for j1.
  half2_t E0[64], E1[64];
  #pragma unroll 8
  for (int k = 0; k < 64; ++k) {
    const float2 ta = *(const float2*)&trans[(2 * k)     * Tc + j0];
    const float2 tb = *(const float2*)&trans[(2 * k + 1) * Tc + j0];
    union { unsigned u; half2_t h; } c0, c1;
    c0.u = pack_h2(__expf(ta.x), __expf(tb.x));
    c1.u = pack_h2(__expf(ta.y), __expf(tb.y));
    E0[k] = c0.h;
    E1[k] = c1.h;
  }

  // ---------------- init t = 0 ----------------
  const size_t strideT = (size_t)Bc * Tc;
  const float* emrow = emis + (size_t)b * Tc;      // em[0,b,:]
  const float2 em00 = *(const float2*)&emrow[j0];
  float lp0a = startT[j0] + em00.x;
  float lp0b = startT[j1] + em00.y;
  float wm = fmaxf(lp0a, lp0b);
  #pragma unroll
  for (int o = 1; o < 64; o <<= 1) wm = fmaxf(wm, __shfl_xor(wm, o));
  const float M0 = wm;
  float pA = __expf(lp0a - M0);
  float pB = __expf(lp0b - M0);
  p_lds[0][l] = pack_h2(pA, pB);

  // prefetch t=1 emission + mask
  emrow += strideT;
  float2 emC = *(const float2*)&emrow[j0];
  int    mC  = mask[Bc + b];

  // ---------------- forward recurrence: no barriers, 1 wave ----------------
  int Ksum = 0;
  int buf  = 0;
  for (int t = 1; t < Lc; ++t) {
    // p broadcast: 16x ds_read_b128, all lanes same address (conflict-free)
    uint4 pr[16];
    const uint4* pv = (const uint4*)p_lds[buf];
    #pragma unroll
    for (int q = 0; q < 16; ++q) pr[q] = pv[q];

    const float eE0 = __expf(emC.x);
    const float eE1 = __expf(emC.y);

    // prefetch next emission + mask (off critical path)
    float2 emN = emC;
    int    mN  = mC;
    if (t + 1 < Lc) {
      emrow += strideT;
      emN = *(const float2*)&emrow[j0];
      mN  = mask[(size_t)(t + 1) * Bc + b];
    }

    // s_j = sum_i p_i * E_ij  — 128 dot2, 8 independent chains of 16
    float s0a = 0.f, s0b = 0.f, s0c = 0.f, s0d = 0.f;
    float s1a = 0.f, s1b = 0.f, s1c = 0.f, s1d = 0.f;
    #pragma unroll
    for (int q = 0; q < 16; ++q) {
      union { unsigned u; half2_t h; } h0, h1, h2, h3;
      h0.u = pr[q].x; h1.u = pr[q].y; h2.u = pr[q].z; h3.u = pr[q].w;
      s0a = fdot2(h0.h, E0[4 * q + 0], s0a);
      s1a = fdot2(h0.h, E1[4 * q + 0], s1a);
      s0b = fdot2(h1.h, E0[4 * q + 1], s0b);
      s1b = fdot2(h1.h, E1[4 * q + 1], s1b);
      s0c = fdot2(h2.h, E0[4 * q + 2], s0c);
      s1c = fdot2(h2.h, E1[4 * q + 2], s1c);
      s0d = fdot2(h3.h, E0[4 * q + 3], s0d);
      s1d = fdot2(h3.h, E1[4 * q + 3], s1d);
    }
    float p0n = ((s0a + s0b) + (s0c + s0d)) * eE0;
    float p1n = ((s1a + s1b) + (s1c + s1d)) * eE1;
    if (!mC) { p0n = pA; p1n = pB; }

    // uniform rescale by 2^-e0, e0 = exponent of lane0's p0n (SALU broadcast)
    const unsigned bits = (unsigned)__builtin_amdgcn_readfirstlane((int)__float_as_uint(p0n));
    int e0 = (int)((bits >> 23) & 0xff) - 127;
    e0 = min(max(e0, -126), 126);
    const float r = __uint_as_float((unsigned)(127 - e0) << 23);  // 2^-e0 exact
    Ksum += e0;
    pA = p0n * r;
    pB = p1n * r;
    p_lds[buf ^ 1][l] = pack_h2(pA, pB);

    emC = emN;
    mC  = mN;
    buf ^= 1;
  }

  // ---------------- final LSE ----------------
  float contrib = pA * __expf(endT[j0]) + pB * __expf(endT[j1]);
  #pragma unroll
  for (int o = 1; o < 64; o <<= 1) contrib += __shfl_xor(contrib, o);
  if (l == 0) {
    const float denom = M0 + (float)Ksum * 0.69314718055994531f + __logf(contrib);
    partial[b] = score - denom;
  }
}

// Deterministic final reduction of 256 per-batch llh values -> scalar.
__global__ void crf_reduce(const float* __restrict__ partial, float* __restrict__ out)
{
  const int tid = threadIdx.x;  // 256 threads
  float v = partial[tid];
  #pragma unroll
  for (int o = 1; o < 64; o <<= 1) v += __shfl_xor(v, o);
  __shared__ float ws[4];
  if ((tid & 63) == 0) ws[tid >> 6] = v;
  __syncthreads();
  if (tid == 0) out[0] = (ws[0] + ws[1]) + (ws[2] + ws[3]);
}

extern "C" void kernel_launch(void* const* d_in, const int* in_sizes, int n_in,
                              void* d_out, int out_size, void* d_ws, size_t ws_size,
                              hipStream_t stream)
{
  const float* emis   = (const float*)d_in[0];
  const int*   tags   = (const int*)d_in[1];
  const int*   mask   = (const int*)d_in[2];
  const float* startT = (const float*)d_in[3];
  const float* endT   = (const float*)d_in[4];
  const float* trans  = (const float*)d_in[5];

  float* partial = (float*)d_ws;  // 256 floats

  crf_llh_kernel<<<Bc, 64, 0, stream>>>(emis, tags, mask, startT, endT, trans, partial);
  crf_reduce<<<1, Bc, 0, stream>>>(partial, (float*)d_out);
}

// Round 6
// 239.127 us; speedup vs baseline: 1.4216x; 1.4216x over previous
//
#include <hip/hip_runtime.h>

static constexpr int Lc = 512;
static constexpr int Bc = 256;
static constexpr int Tc = 128;

typedef _Float16 half2_t __attribute__((ext_vector_type(2)));
typedef __fp16   fp16x2_t __attribute__((ext_vector_type(2)));   // builtin's type

__device__ __forceinline__ float fdot2(half2_t a, half2_t b, float c) {
#if __has_builtin(__builtin_amdgcn_fdot2)
  return __builtin_amdgcn_fdot2(a, b, c, false);
#else
  return fmaf((float)a[0], (float)b[0], fmaf((float)a[1], (float)b[1], c));
#endif
}

__device__ __forceinline__ unsigned pack_h2(float a, float b) {
  union { fp16x2_t h; unsigned u; } cv;
  cv.h = __builtin_amdgcn_cvt_pkrtz(a, b);   // v_cvt_pkrtz_f16_f32
  return cv.u;
}

// ONE WAVE per batch element: 256 blocks x 64 threads. No __syncthreads in
// the recurrence; single-wave LDS round-trip broadcasts p each step.
// Lane l owns output tags j0=2l, j1=2l+1 with the FULL i-reduction done via
// v_dot2_f32_f16 against an f16 E-column pair held in 128 VGPRs.
// NOTE: E-init loop MUST be fully unrolled — partial unroll leaves E0[k]
// runtime-indexed and the compiler allocates it in scratch (R5: VGPR=84,
// WRITE_SIZE=8.2MB, 340us).
__launch_bounds__(64, 1)
__global__ void crf_llh_kernel(const float* __restrict__ emis,
                               const int* __restrict__ tags,
                               const int* __restrict__ mask,
                               const float* __restrict__ startT,
                               const float* __restrict__ endT,
                               const float* __restrict__ trans,
                               float* __restrict__ partial)
{
  const int b  = blockIdx.x;
  const int l  = threadIdx.x;       // lane 0..63
  const int j0 = 2 * l;
  const int j1 = 2 * l + 1;

  __shared__ __align__(16) unsigned p_lds[2][64];   // packed f16x2, 2x256B

  // ---------------- numerator (gold-path score), 8 t's per lane ----------
  float v = 0.f, c = 0.f;
  for (int t = l; t < Lc; t += 64) {
    const float mf  = (float)mask[t * Bc + b];
    const int tag_t = tags[t * Bc + b];
    float e = emis[((size_t)t * Bc + b) * Tc + tag_t] * mf;
    if (t >= 1) e += trans[tags[(t - 1) * Bc + b] * Tc + tag_t] * mf;
    v += e; c += mf;
  }
  #pragma unroll
  for (int o = 1; o < 64; o <<= 1) {
    v += __shfl_xor(v, o);
    c += __shfl_xor(c, o);
  }
  float score = 0.f;   // valid on lane 0
  if (l == 0) {
    const int last_idx = (int)(c + 0.5f) - 1;
    score = v + startT[tags[b]] + endT[tags[last_idx * Bc + b]];
  }

  // ---------------- E columns as f16 pairs: 128 VGPRs ----------------
  // E0[k] = (exp(tr[2k][j0]), exp(tr[2k+1][j0])), same for j1.
  // FULL unroll: every index compile-time -> registers, not scratch.
  half2_t E0[64], E1[64];
  #pragma unroll
  for (int k = 0; k < 64; ++k) {
    const float2 ta = *(const float2*)&trans[(2 * k)     * Tc + j0];
    const float2 tb = *(const float2*)&trans[(2 * k + 1) * Tc + j0];
    union { unsigned u; half2_t h; } c0, c1;
    c0.u = pack_h2(__expf(ta.x), __expf(tb.x));
    c1.u = pack_h2(__expf(ta.y), __expf(tb.y));
    E0[k] = c0.h;
    E1[k] = c1.h;
  }

  // ---------------- init t = 0 ----------------
  const size_t strideT = (size_t)Bc * Tc;
  const float* emrow = emis + (size_t)b * Tc;      // em[0,b,:]
  const float2 em00 = *(const float2*)&emrow[j0];
  float lp0a = startT[j0] + em00.x;
  float lp0b = startT[j1] + em00.y;
  float wm = fmaxf(lp0a, lp0b);
  #pragma unroll
  for (int o = 1; o < 64; o <<= 1) wm = fmaxf(wm, __shfl_xor(wm, o));
  const float M0 = wm;
  float pA = __expf(lp0a - M0);
  float pB = __expf(lp0b - M0);
  p_lds[0][l] = pack_h2(pA, pB);

  // prefetch t=1 emission + mask
  emrow += strideT;
  float2 emC = *(const float2*)&emrow[j0];
  int    mC  = mask[Bc + b];

  // ---------------- forward recurrence: no barriers, 1 wave ----------------
  int Ksum = 0;
  int buf  = 0;
  for (int t = 1; t < Lc; ++t) {
    // p broadcast: 16x ds_read_b128, all lanes same address (conflict-free)
    uint4 pr[16];
    const uint4* pv = (const uint4*)p_lds[buf];
    #pragma unroll
    for (int q = 0; q < 16; ++q) pr[q] = pv[q];

    const float eE0 = __expf(emC.x);
    const float eE1 = __expf(emC.y);

    // prefetch next emission + mask (off critical path)
    float2 emN = emC;
    int    mN  = mC;
    if (t + 1 < Lc) {
      emrow += strideT;
      emN = *(const float2*)&emrow[j0];
      mN  = mask[(size_t)(t + 1) * Bc + b];
    }

    // s_j = sum_i p_i * E_ij  — 128 dot2, 8 independent chains of 16
    float s0a = 0.f, s0b = 0.f, s0c = 0.f, s0d = 0.f;
    float s1a = 0.f, s1b = 0.f, s1c = 0.f, s1d = 0.f;
    #pragma unroll
    for (int q = 0; q < 16; ++q) {
      union { unsigned u; half2_t h; } h0, h1, h2, h3;
      h0.u = pr[q].x; h1.u = pr[q].y; h2.u = pr[q].z; h3.u = pr[q].w;
      s0a = fdot2(h0.h, E0[4 * q + 0], s0a);
      s1a = fdot2(h0.h, E1[4 * q + 0], s1a);
      s0b = fdot2(h1.h, E0[4 * q + 1], s0b);
      s1b = fdot2(h1.h, E1[4 * q + 1], s1b);
      s0c = fdot2(h2.h, E0[4 * q + 2], s0c);
      s1c = fdot2(h2.h, E1[4 * q + 2], s1c);
      s0d = fdot2(h3.h, E0[4 * q + 3], s0d);
      s1d = fdot2(h3.h, E1[4 * q + 3], s1d);
    }
    float p0n = ((s0a + s0b) + (s0c + s0d)) * eE0;
    float p1n = ((s1a + s1b) + (s1c + s1d)) * eE1;
    if (!mC) { p0n = pA; p1n = pB; }

    // uniform rescale by 2^-e0, e0 = exponent of lane0's p0n (SALU broadcast)
    const unsigned bits = (unsigned)__builtin_amdgcn_readfirstlane((int)__float_as_uint(p0n));
    int e0 = (int)((bits >> 23) & 0xff) - 127;
    e0 = min(max(e0, -126), 126);
    const float r = __uint_as_float((unsigned)(127 - e0) << 23);  // 2^-e0 exact
    Ksum += e0;
    pA = p0n * r;
    pB = p1n * r;
    p_lds[buf ^ 1][l] = pack_h2(pA, pB);

    emC = emN;
    mC  = mN;
    buf ^= 1;
  }

  // ---------------- final LSE ----------------
  float contrib = pA * __expf(endT[j0]) + pB * __expf(endT[j1]);
  #pragma unroll
  for (int o = 1; o < 64; o <<= 1) contrib += __shfl_xor(contrib, o);
  if (l == 0) {
    const float denom = M0 + (float)Ksum * 0.69314718055994531f + __logf(contrib);
    partial[b] = score - denom;
  }
}

// Deterministic final reduction of 256 per-batch llh values -> scalar.
__global__ void crf_reduce(const float* __restrict__ partial, float* __restrict__ out)
{
  const int tid = threadIdx.x;  // 256 threads
  float v = partial[tid];
  #pragma unroll
  for (int o = 1; o < 64; o <<= 1) v += __shfl_xor(v, o);
  __shared__ float ws[4];
  if ((tid & 63) == 0) ws[tid >> 6] = v;
  __syncthreads();
  if (tid == 0) out[0] = (ws[0] + ws[1]) + (ws[2] + ws[3]);
}

extern "C" void kernel_launch(void* const* d_in, const int* in_sizes, int n_in,
                              void* d_out, int out_size, void* d_ws, size_t ws_size,
                              hipStream_t stream)
{
  const float* emis   = (const float*)d_in[0];
  const int*   tags   = (const int*)d_in[1];
  const int*   mask   = (const int*)d_in[2];
  const float* startT = (const float*)d_in[3];
  const float* endT   = (const float*)d_in[4];
  const float* trans  = (const float*)d_in[5];

  float* partial = (float*)d_ws;  // 256 floats

  crf_llh_kernel<<<Bc, 64, 0, stream>>>(emis, tags, mask, startT, endT, trans, partial);
  crf_reduce<<<1, Bc, 0, stream>>>(partial, (float*)d_out);
}